// Round 9
// baseline (269.631 us; speedup 1.0000x reference)
//
#include <hip/hip_runtime.h>
#include <math.h>

// Problem constants: B=512, C=50000, D=256.
#define D_DIM 256
#define GTM 64    // gemm tile M
#define GTN 64    // gemm tile N
#define BK 32     // K-tile depth (bf16); 8 K-iterations
#define NB 782    // n-blocks (50000/64 rounded up)
#define NBP 784   // padded partial stride
#define CBPR 7    // compress blocks per row (7*256 thr*32 cols = 57344 >= 50000)
#define CBLKS (CBPR * 512)   // 3584 compress-role blocks

typedef __attribute__((ext_vector_type(8))) short short8;
typedef __attribute__((ext_vector_type(4))) float floatx4;
typedef unsigned long long u64;

__device__ __forceinline__ unsigned short f2bf(float f) {
    unsigned int u = __float_as_uint(f);
    u += 0x7FFFu + ((u >> 16) & 1u);   // round-to-nearest-even
    return (unsigned short)(u >> 16);
}

// async global->LDS 16B: lane l's 16B lands at ldsbase + l*16 (wave-uniform base)
__device__ __forceinline__ void gload16(const void* g, void* lds) {
    __builtin_amdgcn_global_load_lds(
        (const __attribute__((address_space(1))) unsigned int*)g,
        (__attribute__((address_space(3))) unsigned int*)lds, 16, 0, 0);
}

// ---- kernel 1: fused label-compress (role A) + norms/bf16-convert/loadedmask (role B)
// Compress: thread t packs 32 contiguous label ints -> one u32 of bits (no cross-lane
// ops); little-endian u32 store == same memory image as the u64 ballot words.
__global__ __launch_bounds__(256) void prep_compress(
    const float* __restrict__ V, const float* __restrict__ T,
    const int* __restrict__ label, const int* __restrict__ ids,
    u64* __restrict__ loadedmask, u64* __restrict__ posmask,
    unsigned short* __restrict__ Vb, unsigned short* __restrict__ Tb,
    float* __restrict__ gaccum, unsigned int* __restrict__ gcount,
    int B, int C, int n_loaded, int WPR) {
    const int bid = blockIdx.x;
    const int tid = threadIdx.x;
    const int lane = tid & 63;

    if (bid < CBLKS) {   // ---- compress role: 102 MB label stream -> 3.2 MB raw posmask
        int row = bid / CBPR;
        int sub = bid - row * CBPR;
        int u32idx = sub * 256 + tid;          // u32 slot within row (stride 2*WPR)
        int base = u32idx * 32;                // first col of this thread
        const int* lp = label + (size_t)row * C;
        unsigned int* prow = (unsigned int*)(posmask + (size_t)row * WPR);
        if (base + 32 <= C) {                  // fast path: 8 int4 loads in flight
            int4 q[8];
            #pragma unroll
            for (int j = 0; j < 8; ++j) q[j] = *(const int4*)(lp + base + j * 4);
            unsigned int word = 0;
            #pragma unroll
            for (int j = 0; j < 8; ++j) {
                unsigned int nib = (q[j].x ? 1u : 0u) | (q[j].y ? 2u : 0u) |
                                   (q[j].z ? 4u : 0u) | (q[j].w ? 8u : 0u);
                word |= nib << (j * 4);
            }
            prow[u32idx] = word;
        } else if (u32idx < 2 * WPR) {         // tail: masked scalar (few threads)
            unsigned int word = 0;
            for (int j = 0; j < 32; ++j) {
                int col = base + j;
                if (col < C && lp[col]) word |= 1u << j;
            }
            prow[u32idx] = word;
        }
        return;
    }

    // ---- prep role: loadedmask (binary search over sorted ids) + normalize -> bf16
    int ptid = (bid - CBLKS) * 256 + tid;
    if (ptid == 0) { *gcount = 0u; *gaccum = 0.f; }   // zero reduce scratch each call
    if (ptid < WPR) {
        int base = ptid << 6;
        int lo = 0, hi = n_loaded;
        while (lo < hi) { int mid = (lo + hi) >> 1; if (ids[mid] < base) lo = mid + 1; else hi = mid; }
        u64 m = 0;
        for (int i = lo; i < n_loaded; ++i) {
            int v = ids[i]; if (v >= base + 64) break;
            m |= 1ull << (v - base);
        }
        loadedmask[ptid] = m;
    }
    // two rows per wave: 2 loads in flight, 2 independent butterflies
    int pwave = (bid - CBLKS) * 4 + (tid >> 6);
    int r0 = pwave * 2;
    if (r0 >= B + C) return;
    float4 x[2];
    #pragma unroll
    for (int q = 0; q < 2; ++q) {
        int wv = r0 + q;
        if (wv < B + C) {
            const float* src = (wv < B) ? (V + (size_t)wv * D_DIM)
                                        : (T + (size_t)(wv - B) * D_DIM);
            x[q] = ((const float4*)src)[lane];
        }
    }
    #pragma unroll
    for (int q = 0; q < 2; ++q) {
        int wv = r0 + q;
        if (wv >= B + C) break;
        bool isV = wv < B;
        float ss = x[q].x * x[q].x + x[q].y * x[q].y + x[q].z * x[q].z + x[q].w * x[q].w;
        #pragma unroll
        for (int off = 32; off > 0; off >>= 1) ss += __shfl_xor(ss, off);
        float nrm = sqrtf(ss);
        float s = isV ? (1.0f / nrm) : (1.0f / (1e-6f + nrm));  // eps on text norms only
        ushort4 o;
        o.x = f2bf(x[q].x * s); o.y = f2bf(x[q].y * s);
        o.z = f2bf(x[q].z * s); o.w = f2bf(x[q].w * s);
        unsigned short* dst = isV ? (Vb + (size_t)wv * D_DIM)
                                  : (Tb + (size_t)(wv - B) * D_DIM);
        ((ushort4*)dst)[lane] = o;
    }
}

// ---- kernel 2: 64x64-tile bf16 MFMA + raw-posmask epilogue --------------------------
// grid = (8, 782), m fastest: co-resident blocks share B-tiles in L2. Small tiles ->
// acc = 16 VGPR/wave -> high occupancy; all data L2/L3-resident after kernel 1.
__global__ __launch_bounds__(256) void gemm_fused(
    const unsigned short* __restrict__ Vb, const unsigned short* __restrict__ Tb,
    const u64* __restrict__ posmask, const u64* __restrict__ loadedmask,
    float* __restrict__ denomP, float* __restrict__ posP, int C, int WPR) {
    __shared__ unsigned short As[GTM * BK];   // 4 KB, [row][32] (global_load_lds layout)
    __shared__ unsigned short Bs[GTN * BK];   // 4 KB
    __shared__ float sDen[GTM], sPos[GTM];

    const int tid  = threadIdx.x;
    const int lane = tid & 63;
    const int w    = tid >> 6;
    const int m0 = blockIdx.x * GTM;
    const int n0 = blockIdx.y * GTN;

    if (tid < GTM) { sDen[tid] = 0.f; sPos[tid] = 0.f; }

    // ---- staging: wave w stages 16 rows of A and of B per K-tile (1 gload16 each)
    const int sra = lane >> 2;          // row within 16-row group
    const int kc  = (lane & 3) * 8;     // 16B k-chunk
    int ga = m0 + w * 16 + sra;
    int gb = n0 + w * 16 + sra;
    if (gb >= C) gb = C - 1;            // OOB rows: valid address, masked in epilogue
    const unsigned short* gA = Vb + (size_t)ga * D_DIM + kc;
    const unsigned short* gB = Tb + (size_t)gb * D_DIM + kc;
    unsigned short* lA = &As[w * 16 * BK];
    unsigned short* lB = &Bs[w * 16 * BK];

    // ---- compute mapping: 2x2 waves, each 32x32 via 2x2 frags of 16x16x32
    const int wm = (w >> 1) * 32;
    const int wn = (w & 1) * 32;
    const int fr = lane & 15;
    const int quad = lane >> 4;

    floatx4 acc[2][2];
    #pragma unroll
    for (int mi = 0; mi < 2; mi++)
        #pragma unroll
        for (int ni = 0; ni < 2; ni++) acc[mi][ni] = (floatx4)0.f;

    #pragma unroll
    for (int kt = 0; kt < D_DIM / BK; ++kt) {
        if (kt) __syncthreads();
        gload16(gA + kt * BK, lA);
        gload16(gB + kt * BK, lB);
        __syncthreads();                // drains vmcnt before barrier
        short8 af[2], bf[2];
        #pragma unroll
        for (int mi = 0; mi < 2; mi++)
            af[mi] = *(const short8*)&As[(wm + mi * 16 + fr) * BK + quad * 8];
        #pragma unroll
        for (int ni = 0; ni < 2; ni++)
            bf[ni] = *(const short8*)&Bs[(wn + ni * 16 + fr) * BK + quad * 8];
        #pragma unroll
        for (int mi = 0; mi < 2; mi++)
            #pragma unroll
            for (int ni = 0; ni < 2; ni++)
                acc[mi][ni] = __builtin_amdgcn_mfma_f32_16x16x32_bf16(
                    af[mi], bf[ni], acc[mi][ni], 0, 0, 0);
    }

    // ---- epilogue: D layout row = quad*4 + reg, col = lane&15 per 16x16 frag.
    const int wordIdx = n0 >> 6;              // whole block = one 64-col mask word
    const u64 loadedw = loadedmask[wordIdx];
    #pragma unroll
    for (int mi = 0; mi < 2; mi++) {
        #pragma unroll
        for (int i = 0; i < 4; i++) {
            const int mloc = wm + mi * 16 + quad * 4 + i;
            const u64 praw = posmask[(size_t)(m0 + mloc) * WPR + wordIdx];  // L2-hit
            const u64 posw = praw & loadedw;
            const u64 negw = loadedw & ~praw;
            float den = 0.f, pos = 0.f;
            #pragma unroll
            for (int ni = 0; ni < 2; ni++) {
                const float s = acc[mi][ni][i];
                const int bit = wn + ni * 16 + fr;
                if ((negw >> bit) & 1) den += __expf(s);
                if ((posw >> bit) & 1) pos += s;
            }
            #pragma unroll
            for (int off = 8; off >= 1; off >>= 1) {   // reduce 16-lane quad row
                den += __shfl_xor(den, off);
                pos += __shfl_xor(pos, off);
            }
            if (fr == 0) {
                if (den != 0.f) atomicAdd(&sDen[mloc], den);
                if (pos != 0.f) atomicAdd(&sPos[mloc], pos);
            }
        }
    }
    __syncthreads();
    if (tid < GTM) {   // row-major partials: [row][n-block] for coalesced reduce
        denomP[(size_t)(m0 + tid) * NBP + blockIdx.y] = sDen[tid];
        posP[(size_t)(m0 + tid) * NBP + blockIdx.y]   = sPos[tid];
    }
}

// ---- kernel 3: reduce rows + last-block computes the final mean ---------------------
__global__ void reduce_rows(const float* __restrict__ denomP, const float* __restrict__ posP,
                            const u64* __restrict__ posmask, const u64* __restrict__ loadedmask,
                            float* __restrict__ gaccum, unsigned int* __restrict__ gcount,
                            float* __restrict__ out, int B, int WPR) {
    __shared__ float bsum[4];
    int wv   = threadIdx.x >> 6;
    int row  = blockIdx.x * 4 + wv;
    int lane = threadIdx.x & 63;
    float den = 0.f, pos = 0.f;
    int cnt = 0;
    if (row < B) {
        for (int bn = lane; bn < NB; bn += 64) {   // contiguous within row: coalesced
            den += denomP[(size_t)row * NBP + bn];
            pos += posP[(size_t)row * NBP + bn];
        }
        for (int j = lane; j < WPR; j += 64)
            cnt += __popcll(posmask[(size_t)row * WPR + j] & loadedmask[j]);
        #pragma unroll
        for (int off = 32; off > 0; off >>= 1) {
            den += __shfl_xor(den, off);
            pos += __shfl_xor(pos, off);
            cnt += __shfl_xor(cnt, off);
        }
    }
    if (lane == 0) bsum[wv] = (row < B) ? (logf(den) - pos / (float)cnt) : 0.f;
    __syncthreads();
    if (threadIdx.x == 0) {
        float s = bsum[0] + bsum[1] + bsum[2] + bsum[3];
        atomicAdd(gaccum, s);            // 128 ops total: contention negligible
        __threadfence();
        unsigned int old = atomicAdd(gcount, 1u);
        if (old == gridDim.x - 1) {      // last block: all adds complete & visible
            float tot = atomicAdd(gaccum, 0.0f);   // atomic read-back
            out[0] = tot / (float)B;
        }
    }
}

extern "C" void kernel_launch(void* const* d_in, const int* in_sizes, int n_in,
                              void* d_out, int out_size, void* d_ws, size_t ws_size,
                              hipStream_t stream) {
    const float* V     = (const float*)d_in[0];
    const float* T     = (const float*)d_in[1];
    const int*   label = (const int*)d_in[2];
    const int*   ids   = (const int*)d_in[3];
    int B = in_sizes[0] / D_DIM;   // 512
    int C = in_sizes[1] / D_DIM;   // 50000
    int n_loaded = in_sizes[3];    // 40000
    int WPR = (C + 63) >> 6;       // mask words per row (782)

    // ws layout (bytes):
    //   0        : gaccum [1 f], gcount [1 u32]    (pad to 2048)
    //   2048     : loadedmask [782 u64]            (ends 8304; pad to 8320)
    //   8320     : posmask [512*782 u64]           (3,203,072 -> ends 3,211,392)
    //   3211392  : Vb [512*256 bf16]               (262,144 -> ends 3,473,536)
    //   3473536  : Tb [50000*256 bf16]             (25.6 MB -> ends 29,073,536)
    //   29073536 : denomP [512*784 f]              (1,605,632 -> ends 30,679,168)
    //   30679168 : posP                            (ends 32,284,800)
    char* ws = (char*)d_ws;
    float*        gaccum = (float*)(ws + 0);
    unsigned int* gcount = (unsigned int*)(ws + 8);
    u64*   loadedmask = (u64*)(ws + 2048);
    u64*   posmask    = (u64*)(ws + 8320);
    unsigned short* Vb = (unsigned short*)(ws + 3211392);
    unsigned short* Tb = (unsigned short*)(ws + 3473536);
    float* denomP  = (float*)(ws + 29073536);
    float* posP    = (float*)(ws + 30679168);

    int prep_waves  = (B + C + 1) / 2;                  // 2 rows per wave
    int prep_blocks = (prep_waves + 3) / 4;             // 6314
    prep_compress<<<CBLKS + prep_blocks, 256, 0, stream>>>(
        V, T, label, ids, loadedmask, posmask, Vb, Tb, gaccum, gcount,
        B, C, n_loaded, WPR);

    dim3 grid(B / GTM, NB);   // m fastest: 8 blocks share one T-tile
    gemm_fused<<<grid, 256, 0, stream>>>(Vb, Tb, posmask, loadedmask,
                                         denomP, posP, C, WPR);

    reduce_rows<<<(B + 3) / 4, 256, 0, stream>>>(denomP, posP, posmask, loadedmask,
                                                 gaccum, gcount, (float*)d_out, B, WPR);
}